// Round 11
// baseline (636.730 us; speedup 1.0000x reference)
//
#include <hip/hip_runtime.h>

// Sggnn_23218593202512 — round 11: single-barrier LDS double-buffer.
// R10 evidence: 1 block/CU (108 VGPR + 128 AGPR) -> zero inter-block overlap
// -> every __syncthreads (vmcnt(0) drain) exposes full DMA latency (~12k
// cyc/iter vs 620 cyc MFMA). Rotation: barrier -> issue stage(it+1)->buf^1 ->
// compute(buf): next iter's drain waits ~0 (loads issued a compute-phase ago).
// BK=32, As/Bs 2x16KiB each (64 KiB total), XOR key (r>>1)&3 (2-way = free).
// Affinity symmetry via 16x16-g-tile upper-triangle enumeration (136/256
// blocks; mirrored in wconv). feat stage keeps verified gemm_kernel.

typedef __bf16 bf16;
typedef __attribute__((ext_vector_type(8))) __bf16 bf16x8;
typedef __attribute__((ext_vector_type(4))) float f32x4;

#define EPSV 1e-5f

__device__ __forceinline__ void async_load16(const bf16* g, bf16* l) {
    __builtin_amdgcn_global_load_lds(
        (const __attribute__((address_space(1))) void*)g,
        (__attribute__((address_space(3))) void*)l, 16, 0, 0);
}

__global__ __launch_bounds__(256) void prep_kernel(
    const float* __restrict__ g, const float* __restrict__ b,
    const float* __restrict__ m, const float* __restrict__ v,
    const float* __restrict__ bias, float* __restrict__ scale,
    float* __restrict__ offset, int n)
{
    int i = blockIdx.x * 256 + threadIdx.x;
    if (i >= n) return;
    float s = g[i] / sqrtf(v[i] + EPSV);
    float o = b[i] - m[i] * s;
    if (bias) o += bias[i] * s;
    scale[i] = s;
    offset[i] = o;
}

__global__ __launch_bounds__(256) void wtrans_kernel(
    const float* __restrict__ in, bf16* __restrict__ out, int K, int N)
{
    int k = blockIdx.x * 256 + threadIdx.x;
    int n = blockIdx.y;
    out[(size_t)n * K + k] = (bf16)in[(size_t)k * N + n];
}

// wT[g2*256+g1] = bf16(w[g1][g2] + scl_b); only g-tiles ta<=tb computed,
// mirror otherwise (w symmetric).
__global__ __launch_bounds__(256) void wconv_kernel(
    const float* __restrict__ w_acc, const float* __restrict__ sclb,
    bf16* __restrict__ wT)
{
    int tid = blockIdx.x * 256 + threadIdx.x;
    int g2 = tid >> 8, g1 = tid & 255;
    int idx = ((g1 >> 4) <= (g2 >> 4)) ? (g1 * 256 + g2) : (g2 * 256 + g1);
    wT[tid] = (bf16)(w_acc[idx] + sclb[0]);
}

__global__ __launch_bounds__(256) void utrans_kernel(
    const bf16* __restrict__ u, bf16* __restrict__ uT)
{
    __shared__ float tile[64][65];
    int g0 = blockIdx.x * 64, h0 = blockIdx.y * 64, p = blockIdx.z;
    const bf16* up = u + (size_t)p * 256 * 512;
    bf16* op = uT + (size_t)p * 512 * 256;
    for (int c = threadIdx.x; c < 512; c += 256) {
        int r = c >> 3, hc = (c & 7) * 8;
        bf16x8 val = *(const bf16x8*)(up + (size_t)(g0 + r) * 512 + h0 + hc);
#pragma unroll
        for (int j = 0; j < 8; ++j) tile[r][hc + j] = (float)val[j];
    }
    __syncthreads();
    for (int c = threadIdx.x; c < 512; c += 256) {
        int hr = c >> 3, gc = (c & 7) * 8;
        bf16x8 val;
#pragma unroll
        for (int j = 0; j < 8; ++j) val[j] = (bf16)tile[gc + j][hr];
        *(bf16x8*)(op + (size_t)(h0 + hr) * 256 + g0 + gc) = val;
    }
}

__global__ __launch_bounds__(256) void finout_kernel(
    const float* __restrict__ acc, const float* __restrict__ clsb,
    float* __restrict__ out)
{
    int i = blockIdx.x * 256 + threadIdx.x;
    out[i] = acc[i] + clsb[0];
}

// ---------- gemm256 dbuf: C[M,N] = epi(A[M,K] @ BT[N,K]^T) -----------------
// 256x256 block tile, 512 thr = 8 waves (2 row x 4 col), wave 128x64
// (acc[8][4]). BK=32, double-buffered 16KiB As/Bs. LDS slot s at row r holds
// global chunk s ^ ((r>>1)&3)  (2-way bank aliasing only = free).
// Rotation: barrier -> stage(it+1)->buf^1 -> compute(buf). One barrier/iter.
// pair mode (pairX!=0, f32): A row r from (g1,g2): tri? 16x16 g-tile decode
// : gr=rowOff+row0+r, g1=gr>>8, g2=gr&255.
// fuse (fuseW!=0, tri): rs += lrelu(bn(val))*fuseW[col] -> w_acc[g1*256+g2].
__global__ __launch_bounds__(512) void gemm256(
    const bf16* __restrict__ A,
    const float* __restrict__ pairX, const float* __restrict__ pairY,
    const float* __restrict__ ps, const float* __restrict__ po,
    const bf16* __restrict__ BT,
    bf16* __restrict__ C,
    int K, int N, int rowOff, int tri,
    const float* __restrict__ scale, const float* __restrict__ offset,
    int lrelu,
    const float* __restrict__ fuseW, float* __restrict__ facc)
{
    __shared__ bf16 As[2][256 * 32];   // 2 x 16 KiB
    __shared__ bf16 Bs[2][256 * 32];
    const int tid  = threadIdx.x;
    const int lane = tid & 63;
    const int wave = tid >> 6;
    const int wrow = wave >> 2, wcol = wave & 3;
    const int q = lane >> 4, l16 = lane & 15;

    int ta = 0, tb = 0;
    if (tri) {
        int rem = blockIdx.y;
        while (rem >= 16 - ta) { rem -= 16 - ta; ++ta; }
        tb = ta + rem;
    }
    const int row0 = blockIdx.y * 256;
    const int col0 = blockIdx.x * 256;

    f32x4 acc[8][4];
#pragma unroll
    for (int mi = 0; mi < 8; ++mi)
#pragma unroll
        for (int ni = 0; ni < 4; ++ni)
#pragma unroll
            for (int e = 0; e < 4; ++e) acc[mi][ni][e] = 0.f;

    auto stage = [&](int kk, int buf) {
        if (pairX) {
#pragma unroll
            for (int t = 0; t < 2; ++t) {
                int idx = t * 512 + tid;        // 1024 tasks: r=idx>>2, ch=idx&3
                int r = idx >> 2, ch = idx & 3;
                int g1, g2;
                if (tri) { g1 = ta * 16 + (r >> 4); g2 = tb * 16 + (r & 15); }
                else     { int gr = rowOff + row0 + r; g1 = gr >> 8; g2 = gr & 255; }
                const float* xp = pairX + (size_t)g1 * K + kk + ch * 8;
                const float* yp = pairY + (size_t)g2 * K + kk + ch * 8;
                f32x4 x0 = *(const f32x4*)xp, x1 = *(const f32x4*)(xp + 4);
                f32x4 y0 = *(const f32x4*)yp, y1 = *(const f32x4*)(yp + 4);
                f32x4 sa = *(const f32x4*)(ps + kk + ch * 8);
                f32x4 sb = *(const f32x4*)(ps + kk + ch * 8 + 4);
                f32x4 oa = *(const f32x4*)(po + kk + ch * 8);
                f32x4 ob = *(const f32x4*)(po + kk + ch * 8 + 4);
                bf16x8 dv;
#pragma unroll
                for (int j = 0; j < 4; ++j) {
                    float d0 = x0[j] - y0[j];
                    float d1 = x1[j] - y1[j];
                    dv[j]     = (bf16)(d0 * d0 * sa[j] + oa[j]);
                    dv[j + 4] = (bf16)(d1 * d1 * sb[j] + ob[j]);
                }
                *(bf16x8*)&As[buf][r * 32 + ((ch ^ ((r >> 1) & 3)) * 8)] = dv;
            }
        } else {
#pragma unroll
            for (int t = 0; t < 2; ++t) {
                int idx = t * 512 + tid;        // dest lane*16-contig per wave
                int r = idx >> 2, sch = idx & 3;
                int gch = sch ^ ((r >> 1) & 3);
                async_load16(A + (size_t)(row0 + r) * K + kk + gch * 8,
                             &As[buf][idx * 8]);
            }
        }
#pragma unroll
        for (int t = 0; t < 2; ++t) {
            int idx = t * 512 + tid;
            int r = idx >> 2, sch = idx & 3;
            int gch = sch ^ ((r >> 1) & 3);
            async_load16(BT + (size_t)(col0 + r) * K + kk + gch * 8,
                         &Bs[buf][idx * 8]);
        }
    };

    const int niter = K >> 5;
    stage(0, 0);
    for (int it = 0; it < niter; ++it) {
        const int cur = it & 1;
        __syncthreads();                    // drains buf[cur] DMAs (old) only
        if (it + 1 < niter) stage((it + 1) << 5, cur ^ 1);

        bf16x8 af[8], bfr[4];
#pragma unroll
        for (int mi = 0; mi < 8; ++mi) {
            int r = wrow * 128 + mi * 16 + l16;
            af[mi] = *(const bf16x8*)&As[cur][r * 32 + ((q ^ ((r >> 1) & 3)) * 8)];
        }
#pragma unroll
        for (int ni = 0; ni < 4; ++ni) {
            int rc = wcol * 64 + ni * 16 + l16;
            bfr[ni] = *(const bf16x8*)&Bs[cur][rc * 32 + ((q ^ ((rc >> 1) & 3)) * 8)];
        }
#pragma unroll
        for (int mi = 0; mi < 8; ++mi)
#pragma unroll
            for (int ni = 0; ni < 4; ++ni)
                acc[mi][ni] = __builtin_amdgcn_mfma_f32_16x16x32_bf16(
                    af[mi], bfr[ni], acc[mi][ni], 0, 0, 0);
    }

    // C/D layout (m89-verified): col = lane&15, row = (lane>>4)*4 + reg
    if (fuseW) {                            // tri mode: -> w_acc[g1*256+g2]
#pragma unroll
        for (int mi = 0; mi < 8; ++mi)
#pragma unroll
            for (int i = 0; i < 4; ++i) {
                float rs = 0.f;
#pragma unroll
                for (int ni = 0; ni < 4; ++ni) {
                    int cc = col0 + wcol * 64 + ni * 16 + l16;
                    float val = acc[mi][ni][i] * scale[cc] + offset[cc];
                    val = val > 0.f ? val : 0.1f * val;
                    rs += val * fuseW[cc];
                }
                rs += __shfl_xor(rs, 1, 64);
                rs += __shfl_xor(rs, 2, 64);
                rs += __shfl_xor(rs, 4, 64);
                rs += __shfl_xor(rs, 8, 64);
                if (l16 == 0) {
                    int r = wrow * 128 + mi * 16 + q * 4 + i;
                    int g1 = ta * 16 + (r >> 4), g2 = tb * 16 + (r & 15);
                    atomicAdd(facc + g1 * 256 + g2, rs);
                }
            }
        return;
    }
#pragma unroll
    for (int mi = 0; mi < 8; ++mi)
#pragma unroll
        for (int ni = 0; ni < 4; ++ni)
#pragma unroll
            for (int i = 0; i < 4; ++i) {
                int r = row0 + wrow * 128 + mi * 16 + q * 4 + i;
                int cc = col0 + wcol * 64 + ni * 16 + l16;
                float val = acc[mi][ni][i];
                if (scale) val = val * scale[cc] + offset[cc];
                if (lrelu) val = val > 0.f ? val : 0.1f * val;
                C[(size_t)r * N + cc] = (bf16)val;
            }
}

// ---------- verified batched gemm for the feat+classifier stage ------------
__global__ __launch_bounds__(256) void gemm_kernel(
    const bf16* __restrict__ A,
    const bf16* __restrict__ BT, bf16* __restrict__ C,
    int K, int N, long long batchB, long long batchC,
    const float* __restrict__ scale, const float* __restrict__ offset,
    int lrelu, const float* __restrict__ fuseW, float* __restrict__ facc,
    long long faccStride)
{
    __shared__ bf16 As[128 * 64];
    __shared__ bf16 Bs[128 * 64];
    const int tid  = threadIdx.x;
    const int lane = tid & 63;
    const int wave = tid >> 6;
    const int wr = wave >> 1, wc = wave & 1;
    const int row0 = blockIdx.y * 128;
    const int col0 = blockIdx.x * 128;
    const int q = lane >> 4, l16 = lane & 15;
    const int drow = lane >> 3;
    const int dsch = lane & 7;

    const bf16* Bp = BT + (size_t)blockIdx.z * (size_t)batchB;
    bf16* Cp = C + (size_t)blockIdx.z * (size_t)batchC;

    f32x4 acc[4][4];
#pragma unroll
    for (int mi = 0; mi < 4; ++mi)
#pragma unroll
        for (int ni = 0; ni < 4; ++ni)
#pragma unroll
            for (int e = 0; e < 4; ++e) acc[mi][ni][e] = 0.f;

    for (int kk = 0; kk < K; kk += 64) {
#pragma unroll
        for (int t = 0; t < 4; ++t) {
            int grp = wave * 4 + t;
            int r = grp * 8 + drow;
            int gch = dsch ^ (r & 7);
            async_load16(A + (size_t)(row0 + r) * K + kk + gch * 8,
                         &As[grp * 512 + lane * 8]);
        }
#pragma unroll
        for (int t = 0; t < 4; ++t) {
            int grp = wave * 4 + t;
            int r = grp * 8 + drow;
            int gch = dsch ^ (r & 7);
            async_load16(Bp + (size_t)(col0 + r) * K + kk + gch * 8,
                         &Bs[grp * 512 + lane * 8]);
        }
        __syncthreads();
#pragma unroll
        for (int s = 0; s < 2; ++s) {
            bf16x8 af[4], bfr[4];
#pragma unroll
            for (int mi = 0; mi < 4; ++mi) {
                int r = wr * 64 + mi * 16 + l16;
                af[mi] = *(const bf16x8*)&As[r * 64 + (((s * 4 + q) ^ (r & 7)) * 8)];
            }
#pragma unroll
            for (int ni = 0; ni < 4; ++ni) {
                int rc = wc * 64 + ni * 16 + l16;
                bfr[ni] = *(const bf16x8*)&Bs[rc * 64 + (((s * 4 + q) ^ (rc & 7)) * 8)];
            }
#pragma unroll
            for (int mi = 0; mi < 4; ++mi)
#pragma unroll
                for (int ni = 0; ni < 4; ++ni)
                    acc[mi][ni] = __builtin_amdgcn_mfma_f32_16x16x32_bf16(
                        af[mi], bfr[ni], acc[mi][ni], 0, 0, 0);
        }
        __syncthreads();
    }

    if (fuseW) {
#pragma unroll
        for (int mi = 0; mi < 4; ++mi)
#pragma unroll
            for (int i = 0; i < 4; ++i) {
                float rs = 0.f;
#pragma unroll
                for (int ni = 0; ni < 4; ++ni) {
                    int cc = col0 + wc * 64 + ni * 16 + l16;
                    float val = acc[mi][ni][i] * scale[cc] + offset[cc];
                    val = val > 0.f ? val : 0.1f * val;
                    rs += val * fuseW[cc];
                }
                rs += __shfl_xor(rs, 1, 64);
                rs += __shfl_xor(rs, 2, 64);
                rs += __shfl_xor(rs, 4, 64);
                rs += __shfl_xor(rs, 8, 64);
                if (l16 == 0) {
                    int r = row0 + wr * 64 + mi * 16 + q * 4 + i;
                    atomicAdd(facc + (size_t)blockIdx.z * faccStride + r, rs);
                }
            }
        return;
    }
#pragma unroll
    for (int mi = 0; mi < 4; ++mi)
#pragma unroll
        for (int ni = 0; ni < 4; ++ni)
#pragma unroll
            for (int i = 0; i < 4; ++i) {
                int r = row0 + wr * 64 + mi * 16 + q * 4 + i;
                int cc = col0 + wc * 64 + ni * 16 + l16;
                float val = acc[mi][ni][i];
                if (scale) val = val * scale[cc] + offset[cc];
                if (lrelu) val = val > 0.f ? val : 0.1f * val;
                Cp[(size_t)r * N + cc] = (bf16)val;
            }
}

extern "C" void kernel_launch(void* const* d_in, const int* in_sizes, int n_in,
                              void* d_out, int out_size, void* d_ws, size_t ws_size,
                              hipStream_t stream)
{
    const float* f_p   = (const float*)d_in[0];
    const float* f_g   = (const float*)d_in[1];
    const float* bn_g  = (const float*)d_in[2];
    const float* bn_b  = (const float*)d_in[3];
    const float* bn_m  = (const float*)d_in[4];
    const float* bn_v  = (const float*)d_in[5];
    const float* rf_W1 = (const float*)d_in[6];
    const float* rf_b1 = (const float*)d_in[7];
    const float* rf1_g = (const float*)d_in[8];
    const float* rf1_b = (const float*)d_in[9];
    const float* rf1_m = (const float*)d_in[10];
    const float* rf1_v = (const float*)d_in[11];
    const float* rf_W2 = (const float*)d_in[12];
    const float* rf_b2 = (const float*)d_in[13];
    const float* rf2_g = (const float*)d_in[14];
    const float* rf2_b = (const float*)d_in[15];
    const float* rf2_m = (const float*)d_in[16];
    const float* rf2_v = (const float*)d_in[17];
    const float* sfc_W = (const float*)d_in[18];
    const float* sfc_b = (const float*)d_in[19];
    const float* sbn_g = (const float*)d_in[20];
    const float* sbn_b = (const float*)d_in[21];
    const float* sbn_m = (const float*)d_in[22];
    const float* sbn_v = (const float*)d_in[23];
    const float* scl_W = (const float*)d_in[24];
    const float* scl_b = (const float*)d_in[25];
    const float* ffc_W = (const float*)d_in[26];
    const float* ffc_b = (const float*)d_in[27];
    const float* fbn_g = (const float*)d_in[28];
    const float* fbn_b = (const float*)d_in[29];
    const float* fbn_m = (const float*)d_in[30];
    const float* fbn_v = (const float*)d_in[31];
    const float* cls_W = (const float*)d_in[32];
    const float* cls_b = (const float*)d_in[33];

    const size_t MB = 1ull << 20;
    char* ws = (char*)d_ws;
    float* SC      = (float*)(ws);
    float *s0 = SC,        *o0 = SC + 1024;
    float *s1 = SC + 2048, *o1 = SC + 3072;
    float *s2 = SC + 4096, *o2 = SC + 5120;
    float *s3 = SC + 6144, *o3 = SC + 6656;
    float *s4 = SC + 7168, *o4 = SC + 7680;
    float* w_acc   = (float*)(ws + 65536);       // 256 KiB
    float* out_acc = (float*)(ws + 327680);      // 128 KiB
    bf16* wT       = (bf16*)(ws + 458752);       // 128 KiB
    bf16* W1T      = (bf16*)(ws + 1 * MB);
    bf16* W2T      = (bf16*)(ws + 3 * MB);
    bf16* sfcT     = (bf16*)(ws + 5 * MB);
    bf16* ffcT     = (bf16*)(ws + 6 * MB);

    int nc;
    if      (ws_size >= 170 * MB) nc = 1;        // confirmed since R3
    else if (ws_size >= 90 * MB)  nc = 2;
    else                          nc = 4;
    const int pc = 128 / nc;
    const int R  = pc * 256;
    const size_t hbytes = (size_t)R * 1024 * 2;
    bf16* bufA = (bf16*)(ws + 8 * MB);                    // h, then uT
    bf16* bufB = (bf16*)(ws + 8 * MB + hbytes);           // t
    bf16* bufC = (bf16*)(ws + 8 * MB + 2 * hbytes);       // u

    // 1. BN folds
    prep_kernel<<<dim3(4), 256, 0, stream>>>(bn_g, bn_b, bn_m, bn_v, nullptr, s0, o0, 1024);
    prep_kernel<<<dim3(4), 256, 0, stream>>>(rf1_g, rf1_b, rf1_m, rf1_v, rf_b1, s1, o1, 1024);
    prep_kernel<<<dim3(4), 256, 0, stream>>>(rf2_g, rf2_b, rf2_m, rf2_v, rf_b2, s2, o2, 1024);
    prep_kernel<<<dim3(2), 256, 0, stream>>>(sbn_g, sbn_b, sbn_m, sbn_v, sfc_b, s3, o3, 512);
    prep_kernel<<<dim3(2), 256, 0, stream>>>(fbn_g, fbn_b, fbn_m, fbn_v, ffc_b, s4, o4, 512);

    // 2. weight transposes (f32 -> bf16)
    wtrans_kernel<<<dim3(4, 1024), 256, 0, stream>>>(rf_W1, W1T, 1024, 1024);
    wtrans_kernel<<<dim3(4, 1024), 256, 0, stream>>>(rf_W2, W2T, 1024, 1024);
    wtrans_kernel<<<dim3(4, 512), 256, 0, stream>>>(sfc_W, sfcT, 1024, 512);
    wtrans_kernel<<<dim3(4, 512), 256, 0, stream>>>(ffc_W, ffcT, 1024, 512);

    // 3. zero accumulators (w_acc + out_acc contiguous)
    hipMemsetAsync(ws + 65536, 0, 393216, stream);

    // 4. affinity (symmetric, 16x16-g-tile upper triangle: 136 row-blocks)
    gemm256<<<dim3(2, 136), 512, 0, stream>>>(
        nullptr, f_g, f_g, s0, o0, sfcT, nullptr, 1024, 512, 0, 1,
        s3, o3, 1, scl_W, w_acc);
    // 5. wT[g2][g1] = bf16(w[canon] + scl_b)
    wconv_kernel<<<dim3(256), 256, 0, stream>>>(w_acc, scl_b, wT);

    // 6. probe chunks
    for (int ci = 0; ci < nc; ++ci) {
        // h = lrelu(rf1(d @ W1 + b1))   [R,1024] (pair-fused)
        gemm256<<<dim3(4, R / 256), 512, 0, stream>>>(
            nullptr, f_p, f_g, s0, o0, W1T, bufA, 1024, 1024, ci * R, 0,
            s1, o1, 1, nullptr, nullptr);
        // t = lrelu(rf2(h @ W2 + b2))   [R,1024]
        gemm256<<<dim3(4, R / 256), 512, 0, stream>>>(
            bufA, nullptr, nullptr, nullptr, nullptr, W2T, bufB, 1024, 1024, 0, 0,
            s2, o2, 1, nullptr, nullptr);
        // u = t @ ffc_W                 [R,512]
        gemm256<<<dim3(2, R / 256), 512, 0, stream>>>(
            bufB, nullptr, nullptr, nullptr, nullptr, ffcT, bufC, 1024, 512, 0, 0,
            nullptr, nullptr, 0, nullptr, nullptr);
        // uT[p][h][g] -> bufA (h dead)
        utrans_kernel<<<dim3(4, 8, pc), 256, 0, stream>>>(bufC, bufA);
        // fused feat+classifier -> out_acc
        gemm_kernel<<<dim3(4, 2, pc), 256, 0, stream>>>(
            wT, bufA, nullptr, 256, 512, (long long)512 * 256, 0,
            s4, o4, 1, cls_W, out_acc + (size_t)ci * pc * 256, 256);
    }
    // 7. d_out = out_acc + cls_b
    finout_kernel<<<dim3(128), 256, 0, stream>>>(out_acc, cls_b, (float*)d_out);
}

// Round 12
// 592.242 us; speedup vs baseline: 1.0751x; 1.0751x over previous
//
#include <hip/hip_runtime.h>

// Sggnn_23218593202512 — round 12: R10 (best, 601us) + quantization-aware
// symmetric affinity. R11 showed tri at 256x256 tiles gives 272 blocks on
// 256 CUs -> 2 serial rounds = zero saving. gemm_aff: 256x128 block (8 waves
// of 64x64, acc[4][4]), BK=64, tri decode (R11-verified) + col-split grid
// (4,136)=544 blocks -> 2.125 rounds of half-blocks ~= 1.06x T_half.
// h/t/u keep R10's gemm256 verbatim (161us best). wconv mirrors (R11).

typedef __bf16 bf16;
typedef __attribute__((ext_vector_type(8))) __bf16 bf16x8;
typedef __attribute__((ext_vector_type(4))) float f32x4;

#define EPSV 1e-5f

__device__ __forceinline__ void async_load16(const bf16* g, bf16* l) {
    __builtin_amdgcn_global_load_lds(
        (const __attribute__((address_space(1))) void*)g,
        (__attribute__((address_space(3))) void*)l, 16, 0, 0);
}

__global__ __launch_bounds__(256) void prep_kernel(
    const float* __restrict__ g, const float* __restrict__ b,
    const float* __restrict__ m, const float* __restrict__ v,
    const float* __restrict__ bias, float* __restrict__ scale,
    float* __restrict__ offset, int n)
{
    int i = blockIdx.x * 256 + threadIdx.x;
    if (i >= n) return;
    float s = g[i] / sqrtf(v[i] + EPSV);
    float o = b[i] - m[i] * s;
    if (bias) o += bias[i] * s;
    scale[i] = s;
    offset[i] = o;
}

__global__ __launch_bounds__(256) void wtrans_kernel(
    const float* __restrict__ in, bf16* __restrict__ out, int K, int N)
{
    int k = blockIdx.x * 256 + threadIdx.x;
    int n = blockIdx.y;
    out[(size_t)n * K + k] = (bf16)in[(size_t)k * N + n];
}

// wT[g2*256+g1] = bf16(w[g1][g2] + scl_b); only g-tiles ta<=tb computed,
// mirror otherwise (w symmetric). [R11-verified]
__global__ __launch_bounds__(256) void wconv_kernel(
    const float* __restrict__ w_acc, const float* __restrict__ sclb,
    bf16* __restrict__ wT)
{
    int tid = blockIdx.x * 256 + threadIdx.x;
    int g2 = tid >> 8, g1 = tid & 255;
    int idx = ((g1 >> 4) <= (g2 >> 4)) ? (g1 * 256 + g2) : (g2 * 256 + g1);
    wT[tid] = (bf16)(w_acc[idx] + sclb[0]);
}

__global__ __launch_bounds__(256) void utrans_kernel(
    const bf16* __restrict__ u, bf16* __restrict__ uT)
{
    __shared__ float tile[64][65];
    int g0 = blockIdx.x * 64, h0 = blockIdx.y * 64, p = blockIdx.z;
    const bf16* up = u + (size_t)p * 256 * 512;
    bf16* op = uT + (size_t)p * 512 * 256;
    for (int c = threadIdx.x; c < 512; c += 256) {
        int r = c >> 3, hc = (c & 7) * 8;
        bf16x8 val = *(const bf16x8*)(up + (size_t)(g0 + r) * 512 + h0 + hc);
#pragma unroll
        for (int j = 0; j < 8; ++j) tile[r][hc + j] = (float)val[j];
    }
    __syncthreads();
    for (int c = threadIdx.x; c < 512; c += 256) {
        int hr = c >> 3, gc = (c & 7) * 8;
        bf16x8 val;
#pragma unroll
        for (int j = 0; j < 8; ++j) val[j] = (bf16)tile[gc + j][hr];
        *(bf16x8*)(op + (size_t)(h0 + hr) * 256 + g0 + gc) = val;
    }
}

__global__ __launch_bounds__(256) void finout_kernel(
    const float* __restrict__ acc, const float* __restrict__ clsb,
    float* __restrict__ out)
{
    int i = blockIdx.x * 256 + threadIdx.x;
    out[i] = acc[i] + clsb[0];
}

// ---------- gemm256 (R10-verified, best): 256x256 block, BK=64 -------------
__global__ __launch_bounds__(512) void gemm256(
    const bf16* __restrict__ A,
    const float* __restrict__ pairX, const float* __restrict__ pairY,
    const float* __restrict__ ps, const float* __restrict__ po,
    const bf16* __restrict__ BT,
    bf16* __restrict__ C,
    int K, int N, int rowOff,
    const float* __restrict__ scale, const float* __restrict__ offset,
    int lrelu)
{
    __shared__ bf16 As[256 * 64];   // 32 KiB
    __shared__ bf16 Bs[256 * 64];   // 32 KiB
    const int tid  = threadIdx.x;
    const int lane = tid & 63;
    const int wave = tid >> 6;
    const int wrow = wave >> 2, wcol = wave & 3;
    const int row0 = blockIdx.y * 256;
    const int col0 = blockIdx.x * 256;
    const int q = lane >> 4, l16 = lane & 15;

    f32x4 acc[8][4];
#pragma unroll
    for (int mi = 0; mi < 8; ++mi)
#pragma unroll
        for (int ni = 0; ni < 4; ++ni)
#pragma unroll
            for (int e = 0; e < 4; ++e) acc[mi][ni][e] = 0.f;

    for (int kk = 0; kk < K; kk += 64) {
        if (pairX) {
#pragma unroll
            for (int t = 0; t < 4; ++t) {
                int c = tid + t * 512;      // 2048 tasks: r=c>>3, chunk=c&7
                int r = c >> 3, ch = c & 7;
                int gr = rowOff + row0 + r;
                const float* xp = pairX + (size_t)(gr >> 8) * K + kk + ch * 8;
                const float* yp = pairY + (size_t)(gr & 255) * K + kk + ch * 8;
                f32x4 x0 = *(const f32x4*)xp, x1 = *(const f32x4*)(xp + 4);
                f32x4 y0 = *(const f32x4*)yp, y1 = *(const f32x4*)(yp + 4);
                f32x4 sa = *(const f32x4*)(ps + kk + ch * 8);
                f32x4 sb = *(const f32x4*)(ps + kk + ch * 8 + 4);
                f32x4 oa = *(const f32x4*)(po + kk + ch * 8);
                f32x4 ob = *(const f32x4*)(po + kk + ch * 8 + 4);
                bf16x8 dv;
#pragma unroll
                for (int j = 0; j < 4; ++j) {
                    float d0 = x0[j] - y0[j];
                    float d1 = x1[j] - y1[j];
                    dv[j]     = (bf16)(d0 * d0 * sa[j] + oa[j]);
                    dv[j + 4] = (bf16)(d1 * d1 * sb[j] + ob[j]);
                }
                *(bf16x8*)&As[r * 64 + ((ch ^ (r & 7)) * 8)] = dv;
            }
        } else {
#pragma unroll
            for (int t = 0; t < 4; ++t) {
                int idx = t * 512 + tid;
                int r = idx >> 3, sch = idx & 7;
                int gch = sch ^ (r & 7);
                async_load16(A + (size_t)(row0 + r) * K + kk + gch * 8,
                             &As[idx * 8]);
            }
        }
#pragma unroll
        for (int t = 0; t < 4; ++t) {
            int idx = t * 512 + tid;
            int r = idx >> 3, sch = idx & 7;
            int gch = sch ^ (r & 7);
            async_load16(BT + (size_t)(col0 + r) * K + kk + gch * 8,
                         &Bs[idx * 8]);
        }
        __syncthreads();

#pragma unroll
        for (int s = 0; s < 2; ++s) {
            bf16x8 af[8], bfr[4];
#pragma unroll
            for (int mi = 0; mi < 8; ++mi) {
                int r = wrow * 128 + mi * 16 + l16;
                af[mi] = *(const bf16x8*)&As[r * 64 + (((s * 4 + q) ^ (r & 7)) * 8)];
            }
#pragma unroll
            for (int ni = 0; ni < 4; ++ni) {
                int rc = wcol * 64 + ni * 16 + l16;
                bfr[ni] = *(const bf16x8*)&Bs[rc * 64 + (((s * 4 + q) ^ (rc & 7)) * 8)];
            }
#pragma unroll
            for (int mi = 0; mi < 8; ++mi)
#pragma unroll
                for (int ni = 0; ni < 4; ++ni)
                    acc[mi][ni] = __builtin_amdgcn_mfma_f32_16x16x32_bf16(
                        af[mi], bfr[ni], acc[mi][ni], 0, 0, 0);
        }
        __syncthreads();
    }

    // C/D layout (m89-verified): col = lane&15, row = (lane>>4)*4 + reg
#pragma unroll
    for (int mi = 0; mi < 8; ++mi)
#pragma unroll
        for (int ni = 0; ni < 4; ++ni)
#pragma unroll
            for (int i = 0; i < 4; ++i) {
                int r = row0 + wrow * 128 + mi * 16 + q * 4 + i;
                int cc = col0 + wcol * 64 + ni * 16 + l16;
                float val = acc[mi][ni][i];
                if (scale) val = val * scale[cc] + offset[cc];
                if (lrelu) val = val > 0.f ? val : 0.1f * val;
                C[(size_t)r * N + cc] = (bf16)val;
            }
}

// ---------- gemm_aff: symmetric affinity, 256x128 block, BK=64 -------------
// 512 thr = 8 waves (4 row x 2 col), wave 64x64 (acc[4][4]). Tri decode
// (R11-verified): blockIdx.y -> upper-tri (ta,tb) 16x16-g-tile pair; row r
// <-> (g1=ta*16+(r>>4), g2=tb*16+(r&15)). Grid (4,136)=544 blocks.
// Epilogue: rs += lrelu(bn(val))*sclW[col] -> atomicAdd w_acc[g1*256+g2]
// (col-split across grid.x is linear -> valid).
__global__ __launch_bounds__(512) void gemm_aff(
    const float* __restrict__ pairX,
    const float* __restrict__ ps, const float* __restrict__ po,
    const bf16* __restrict__ BT,
    int K,
    const float* __restrict__ scale, const float* __restrict__ offset,
    const float* __restrict__ sclW, float* __restrict__ w_acc)
{
    __shared__ bf16 As[256 * 64];   // 32 KiB
    __shared__ bf16 Bs[128 * 64];   // 16 KiB
    const int tid  = threadIdx.x;
    const int lane = tid & 63;
    const int wave = tid >> 6;
    const int wrow = wave >> 1, wcol = wave & 1;
    const int q = lane >> 4, l16 = lane & 15;
    const int col0 = blockIdx.x * 128;

    int ta = 0, rem = blockIdx.y;
    while (rem >= 16 - ta) { rem -= 16 - ta; ++ta; }
    const int tb = ta + rem;

    f32x4 acc[4][4];
#pragma unroll
    for (int mi = 0; mi < 4; ++mi)
#pragma unroll
        for (int ni = 0; ni < 4; ++ni)
#pragma unroll
            for (int e = 0; e < 4; ++e) acc[mi][ni][e] = 0.f;

    for (int kk = 0; kk < K; kk += 64) {
        // A: 256 rows x 64 k, pair-construct (dg) from tri decode
#pragma unroll
        for (int t = 0; t < 4; ++t) {
            int c = tid + t * 512;          // 2048 tasks: r=c>>3, ch=c&7
            int r = c >> 3, ch = c & 7;
            int g1 = ta * 16 + (r >> 4), g2 = tb * 16 + (r & 15);
            const float* xp = pairX + (size_t)g1 * K + kk + ch * 8;
            const float* yp = pairX + (size_t)g2 * K + kk + ch * 8;
            f32x4 x0 = *(const f32x4*)xp, x1 = *(const f32x4*)(xp + 4);
            f32x4 y0 = *(const f32x4*)yp, y1 = *(const f32x4*)(yp + 4);
            f32x4 sa = *(const f32x4*)(ps + kk + ch * 8);
            f32x4 sb = *(const f32x4*)(ps + kk + ch * 8 + 4);
            f32x4 oa = *(const f32x4*)(po + kk + ch * 8);
            f32x4 ob = *(const f32x4*)(po + kk + ch * 8 + 4);
            bf16x8 dv;
#pragma unroll
            for (int j = 0; j < 4; ++j) {
                float d0 = x0[j] - y0[j];
                float d1 = x1[j] - y1[j];
                dv[j]     = (bf16)(d0 * d0 * sa[j] + oa[j]);
                dv[j + 4] = (bf16)(d1 * d1 * sb[j] + ob[j]);
            }
            *(bf16x8*)&As[r * 64 + ((ch ^ (r & 7)) * 8)] = dv;
        }
        // B: 128 cols x 64 k, async DMA (same verified idiom)
#pragma unroll
        for (int t = 0; t < 2; ++t) {
            int idx = t * 512 + tid;        // 1024 chunks
            int r = idx >> 3, sch = idx & 7;
            int gch = sch ^ (r & 7);
            async_load16(BT + (size_t)(col0 + r) * K + kk + gch * 8,
                         &Bs[idx * 8]);
        }
        __syncthreads();

#pragma unroll
        for (int s = 0; s < 2; ++s) {
            bf16x8 af[4], bfr[4];
#pragma unroll
            for (int mi = 0; mi < 4; ++mi) {
                int r = wrow * 64 + mi * 16 + l16;
                af[mi] = *(const bf16x8*)&As[r * 64 + (((s * 4 + q) ^ (r & 7)) * 8)];
            }
#pragma unroll
            for (int ni = 0; ni < 4; ++ni) {
                int rc = wcol * 64 + ni * 16 + l16;
                bfr[ni] = *(const bf16x8*)&Bs[rc * 64 + (((s * 4 + q) ^ (rc & 7)) * 8)];
            }
#pragma unroll
            for (int mi = 0; mi < 4; ++mi)
#pragma unroll
                for (int ni = 0; ni < 4; ++ni)
                    acc[mi][ni] = __builtin_amdgcn_mfma_f32_16x16x32_bf16(
                        af[mi], bfr[ni], acc[mi][ni], 0, 0, 0);
        }
        __syncthreads();
    }

    // fused epilogue -> w_acc[g1*256+g2] (C/D layout m89-verified)
#pragma unroll
    for (int mi = 0; mi < 4; ++mi)
#pragma unroll
        for (int i = 0; i < 4; ++i) {
            float rs = 0.f;
#pragma unroll
            for (int ni = 0; ni < 4; ++ni) {
                int cc = col0 + wcol * 64 + ni * 16 + l16;
                float val = acc[mi][ni][i] * scale[cc] + offset[cc];
                val = val > 0.f ? val : 0.1f * val;
                rs += val * sclW[cc];
            }
            rs += __shfl_xor(rs, 1, 64);
            rs += __shfl_xor(rs, 2, 64);
            rs += __shfl_xor(rs, 4, 64);
            rs += __shfl_xor(rs, 8, 64);
            if (l16 == 0) {
                int r = wrow * 64 + mi * 16 + q * 4 + i;
                int g1 = ta * 16 + (r >> 4), g2 = tb * 16 + (r & 15);
                atomicAdd(w_acc + g1 * 256 + g2, rs);
            }
        }
}

// ---------- verified batched gemm for the feat+classifier stage ------------
__global__ __launch_bounds__(256) void gemm_kernel(
    const bf16* __restrict__ A,
    const bf16* __restrict__ BT, bf16* __restrict__ C,
    int K, int N, long long batchB, long long batchC,
    const float* __restrict__ scale, const float* __restrict__ offset,
    int lrelu, const float* __restrict__ fuseW, float* __restrict__ facc,
    long long faccStride)
{
    __shared__ bf16 As[128 * 64];
    __shared__ bf16 Bs[128 * 64];
    const int tid  = threadIdx.x;
    const int lane = tid & 63;
    const int wave = tid >> 6;
    const int wr = wave >> 1, wc = wave & 1;
    const int row0 = blockIdx.y * 128;
    const int col0 = blockIdx.x * 128;
    const int q = lane >> 4, l16 = lane & 15;
    const int drow = lane >> 3;
    const int dsch = lane & 7;

    const bf16* Bp = BT + (size_t)blockIdx.z * (size_t)batchB;
    bf16* Cp = C + (size_t)blockIdx.z * (size_t)batchC;

    f32x4 acc[4][4];
#pragma unroll
    for (int mi = 0; mi < 4; ++mi)
#pragma unroll
        for (int ni = 0; ni < 4; ++ni)
#pragma unroll
            for (int e = 0; e < 4; ++e) acc[mi][ni][e] = 0.f;

    for (int kk = 0; kk < K; kk += 64) {
#pragma unroll
        for (int t = 0; t < 4; ++t) {
            int grp = wave * 4 + t;
            int r = grp * 8 + drow;
            int gch = dsch ^ (r & 7);
            async_load16(A + (size_t)(row0 + r) * K + kk + gch * 8,
                         &As[grp * 512 + lane * 8]);
        }
#pragma unroll
        for (int t = 0; t < 4; ++t) {
            int grp = wave * 4 + t;
            int r = grp * 8 + drow;
            int gch = dsch ^ (r & 7);
            async_load16(Bp + (size_t)(col0 + r) * K + kk + gch * 8,
                         &Bs[grp * 512 + lane * 8]);
        }
        __syncthreads();
#pragma unroll
        for (int s = 0; s < 2; ++s) {
            bf16x8 af[4], bfr[4];
#pragma unroll
            for (int mi = 0; mi < 4; ++mi) {
                int r = wr * 64 + mi * 16 + l16;
                af[mi] = *(const bf16x8*)&As[r * 64 + (((s * 4 + q) ^ (r & 7)) * 8)];
            }
#pragma unroll
            for (int ni = 0; ni < 4; ++ni) {
                int rc = wc * 64 + ni * 16 + l16;
                bfr[ni] = *(const bf16x8*)&Bs[rc * 64 + (((s * 4 + q) ^ (rc & 7)) * 8)];
            }
#pragma unroll
            for (int mi = 0; mi < 4; ++mi)
#pragma unroll
                for (int ni = 0; ni < 4; ++ni)
                    acc[mi][ni] = __builtin_amdgcn_mfma_f32_16x16x32_bf16(
                        af[mi], bfr[ni], acc[mi][ni], 0, 0, 0);
        }
        __syncthreads();
    }

    if (fuseW) {
#pragma unroll
        for (int mi = 0; mi < 4; ++mi)
#pragma unroll
            for (int i = 0; i < 4; ++i) {
                float rs = 0.f;
#pragma unroll
                for (int ni = 0; ni < 4; ++ni) {
                    int cc = col0 + wc * 64 + ni * 16 + l16;
                    float val = acc[mi][ni][i] * scale[cc] + offset[cc];
                    val = val > 0.f ? val : 0.1f * val;
                    rs += val * fuseW[cc];
                }
                rs += __shfl_xor(rs, 1, 64);
                rs += __shfl_xor(rs, 2, 64);
                rs += __shfl_xor(rs, 4, 64);
                rs += __shfl_xor(rs, 8, 64);
                if (l16 == 0) {
                    int r = row0 + wr * 64 + mi * 16 + q * 4 + i;
                    atomicAdd(facc + (size_t)blockIdx.z * faccStride + r, rs);
                }
            }
        return;
    }
#pragma unroll
    for (int mi = 0; mi < 4; ++mi)
#pragma unroll
        for (int ni = 0; ni < 4; ++ni)
#pragma unroll
            for (int i = 0; i < 4; ++i) {
                int r = row0 + wr * 64 + mi * 16 + q * 4 + i;
                int cc = col0 + wc * 64 + ni * 16 + l16;
                float val = acc[mi][ni][i];
                if (scale) val = val * scale[cc] + offset[cc];
                if (lrelu) val = val > 0.f ? val : 0.1f * val;
                Cp[(size_t)r * N + cc] = (bf16)val;
            }
}

extern "C" void kernel_launch(void* const* d_in, const int* in_sizes, int n_in,
                              void* d_out, int out_size, void* d_ws, size_t ws_size,
                              hipStream_t stream)
{
    const float* f_p   = (const float*)d_in[0];
    const float* f_g   = (const float*)d_in[1];
    const float* bn_g  = (const float*)d_in[2];
    const float* bn_b  = (const float*)d_in[3];
    const float* bn_m  = (const float*)d_in[4];
    const float* bn_v  = (const float*)d_in[5];
    const float* rf_W1 = (const float*)d_in[6];
    const float* rf_b1 = (const float*)d_in[7];
    const float* rf1_g = (const float*)d_in[8];
    const float* rf1_b = (const float*)d_in[9];
    const float* rf1_m = (const float*)d_in[10];
    const float* rf1_v = (const float*)d_in[11];
    const float* rf_W2 = (const float*)d_in[12];
    const float* rf_b2 = (const float*)d_in[13];
    const float* rf2_g = (const float*)d_in[14];
    const float* rf2_b = (const float*)d_in[15];
    const float* rf2_m = (const float*)d_in[16];
    const float* rf2_v = (const float*)d_in[17];
    const float* sfc_W = (const float*)d_in[18];
    const float* sfc_b = (const float*)d_in[19];
    const float* sbn_g = (const float*)d_in[20];
    const float* sbn_b = (const float*)d_in[21];
    const float* sbn_m = (const float*)d_in[22];
    const float* sbn_v = (const float*)d_in[23];
    const float* scl_W = (const float*)d_in[24];
    const float* scl_b = (const float*)d_in[25];
    const float* ffc_W = (const float*)d_in[26];
    const float* ffc_b = (const float*)d_in[27];
    const float* fbn_g = (const float*)d_in[28];
    const float* fbn_b = (const float*)d_in[29];
    const float* fbn_m = (const float*)d_in[30];
    const float* fbn_v = (const float*)d_in[31];
    const float* cls_W = (const float*)d_in[32];
    const float* cls_b = (const float*)d_in[33];

    const size_t MB = 1ull << 20;
    char* ws = (char*)d_ws;
    float* SC      = (float*)(ws);
    float *s0 = SC,        *o0 = SC + 1024;
    float *s1 = SC + 2048, *o1 = SC + 3072;
    float *s2 = SC + 4096, *o2 = SC + 5120;
    float *s3 = SC + 6144, *o3 = SC + 6656;
    float *s4 = SC + 7168, *o4 = SC + 7680;
    float* w_acc   = (float*)(ws + 65536);       // 256 KiB
    float* out_acc = (float*)(ws + 327680);      // 128 KiB
    bf16* wT       = (bf16*)(ws + 458752);       // 128 KiB
    bf16* W1T      = (bf16*)(ws + 1 * MB);
    bf16* W2T      = (bf16*)(ws + 3 * MB);
    bf16* sfcT     = (bf16*)(ws + 5 * MB);
    bf16* ffcT     = (bf16*)(ws + 6 * MB);

    int nc;
    if      (ws_size >= 170 * MB) nc = 1;        // confirmed since R3
    else if (ws_size >= 90 * MB)  nc = 2;
    else                          nc = 4;
    const int pc = 128 / nc;
    const int R  = pc * 256;
    const size_t hbytes = (size_t)R * 1024 * 2;
    bf16* bufA = (bf16*)(ws + 8 * MB);                    // h, then uT
    bf16* bufB = (bf16*)(ws + 8 * MB + hbytes);           // t
    bf16* bufC = (bf16*)(ws + 8 * MB + 2 * hbytes);       // u

    // 1. BN folds
    prep_kernel<<<dim3(4), 256, 0, stream>>>(bn_g, bn_b, bn_m, bn_v, nullptr, s0, o0, 1024);
    prep_kernel<<<dim3(4), 256, 0, stream>>>(rf1_g, rf1_b, rf1_m, rf1_v, rf_b1, s1, o1, 1024);
    prep_kernel<<<dim3(4), 256, 0, stream>>>(rf2_g, rf2_b, rf2_m, rf2_v, rf_b2, s2, o2, 1024);
    prep_kernel<<<dim3(2), 256, 0, stream>>>(sbn_g, sbn_b, sbn_m, sbn_v, sfc_b, s3, o3, 512);
    prep_kernel<<<dim3(2), 256, 0, stream>>>(fbn_g, fbn_b, fbn_m, fbn_v, ffc_b, s4, o4, 512);

    // 2. weight transposes (f32 -> bf16)
    wtrans_kernel<<<dim3(4, 1024), 256, 0, stream>>>(rf_W1, W1T, 1024, 1024);
    wtrans_kernel<<<dim3(4, 1024), 256, 0, stream>>>(rf_W2, W2T, 1024, 1024);
    wtrans_kernel<<<dim3(4, 512), 256, 0, stream>>>(sfc_W, sfcT, 1024, 512);
    wtrans_kernel<<<dim3(4, 512), 256, 0, stream>>>(ffc_W, ffcT, 1024, 512);

    // 3. zero accumulators (w_acc + out_acc contiguous)
    hipMemsetAsync(ws + 65536, 0, 393216, stream);

    // 4. symmetric affinity: upper-tri 16x16-g-tiles, 128-col split
    //    grid (4,136) = 544 blocks (~1.06 rounds of half-size blocks)
    gemm_aff<<<dim3(4, 136), 512, 0, stream>>>(
        f_g, s0, o0, sfcT, 1024, s3, o3, scl_W, w_acc);
    // 5. wT[g2][g1] = bf16(w[canon] + scl_b)
    wconv_kernel<<<dim3(256), 256, 0, stream>>>(w_acc, scl_b, wT);

    // 6. probe chunks
    for (int ci = 0; ci < nc; ++ci) {
        // h = lrelu(rf1(d @ W1 + b1))   [R,1024] (pair-fused)
        gemm256<<<dim3(4, R / 256), 512, 0, stream>>>(
            nullptr, f_p, f_g, s0, o0, W1T, bufA, 1024, 1024, ci * R,
            s1, o1, 1);
        // t = lrelu(rf2(h @ W2 + b2))   [R,1024]
        gemm256<<<dim3(4, R / 256), 512, 0, stream>>>(
            bufA, nullptr, nullptr, nullptr, nullptr, W2T, bufB, 1024, 1024, 0,
            s2, o2, 1);
        // u = t @ ffc_W                 [R,512]
        gemm256<<<dim3(2, R / 256), 512, 0, stream>>>(
            bufB, nullptr, nullptr, nullptr, nullptr, ffcT, bufC, 1024, 512, 0,
            nullptr, nullptr, 0);
        // uT[p][h][g] -> bufA (h dead)
        utrans_kernel<<<dim3(4, 8, pc), 256, 0, stream>>>(bufC, bufA);
        // fused feat+classifier -> out_acc
        gemm_kernel<<<dim3(4, 2, pc), 256, 0, stream>>>(
            wT, bufA, nullptr, 256, 512, (long long)512 * 256, 0,
            s4, o4, 1, cls_W, out_acc + (size_t)ci * pc * 256, 256);
    }
    // 7. d_out = out_acc + cls_b
    finout_kernel<<<dim3(128), 256, 0, stream>>>(out_acc, cls_b, (float*)d_out);
}

// Round 13
// 566.694 us; speedup vs baseline: 1.1236x; 1.0451x over previous
//
#include <hip/hip_runtime.h>

// Sggnn_23218593202512 — round 13: structural eliminations on the R12 best
// (592us). (1) uT computed DIRECTLY as batched gemm_bt (A=ffcT, B=t_p):
// u^T = ffc^T t^T, both k-contig -> utrans deleted (numerically identical).
// (2) feat via batched gemm256 (K=256, 4 iters, grid 256 blocks = 1 round,
// cls_W fused epilogue) -> gemm_kernel deleted (~40 -> ~22us).
// gemm256 gains batchA/batchB/batchC + fuse epilogue. h/t/affinity launches
// byte-identical to R12 for clean attribution.

typedef __bf16 bf16;
typedef __attribute__((ext_vector_type(8))) __bf16 bf16x8;
typedef __attribute__((ext_vector_type(4))) float f32x4;

#define EPSV 1e-5f

__device__ __forceinline__ void async_load16(const bf16* g, bf16* l) {
    __builtin_amdgcn_global_load_lds(
        (const __attribute__((address_space(1))) void*)g,
        (__attribute__((address_space(3))) void*)l, 16, 0, 0);
}

__global__ __launch_bounds__(256) void prep_kernel(
    const float* __restrict__ g, const float* __restrict__ b,
    const float* __restrict__ m, const float* __restrict__ v,
    const float* __restrict__ bias, float* __restrict__ scale,
    float* __restrict__ offset, int n)
{
    int i = blockIdx.x * 256 + threadIdx.x;
    if (i >= n) return;
    float s = g[i] / sqrtf(v[i] + EPSV);
    float o = b[i] - m[i] * s;
    if (bias) o += bias[i] * s;
    scale[i] = s;
    offset[i] = o;
}

__global__ __launch_bounds__(256) void wtrans_kernel(
    const float* __restrict__ in, bf16* __restrict__ out, int K, int N)
{
    int k = blockIdx.x * 256 + threadIdx.x;
    int n = blockIdx.y;
    out[(size_t)n * K + k] = (bf16)in[(size_t)k * N + n];
}

// wT[g2*256+g1] = bf16(w[g1][g2] + scl_b); only g-tiles ta<=tb computed,
// mirror otherwise (w symmetric). [R11/R12-verified]
__global__ __launch_bounds__(256) void wconv_kernel(
    const float* __restrict__ w_acc, const float* __restrict__ sclb,
    bf16* __restrict__ wT)
{
    int tid = blockIdx.x * 256 + threadIdx.x;
    int g2 = tid >> 8, g1 = tid & 255;
    int idx = ((g1 >> 4) <= (g2 >> 4)) ? (g1 * 256 + g2) : (g2 * 256 + g1);
    wT[tid] = (bf16)(w_acc[idx] + sclb[0]);
}

__global__ __launch_bounds__(256) void finout_kernel(
    const float* __restrict__ acc, const float* __restrict__ clsb,
    float* __restrict__ out)
{
    int i = blockIdx.x * 256 + threadIdx.x;
    out[i] = acc[i] + clsb[0];
}

// ---------- gemm256 (R10/R12-verified core + batch/fuse): -----------------
// C_z[M,N] = epi(A_z[M,K] @ BT_z[N,K]^T). 256x256 block, 512 thr = 8 waves
// (2 row x 4 col), wave 128x64 (acc[8][4]), BK=64, XOR-swizzled LDS.
// pair mode (pairX!=0): A[r][k]=(X[gr>>8][k]-Y[gr&255][k])^2*ps+po,
//   gr=rowOff+row0+r (not batched).
// fuse (fuseW!=0): rs += lrelu(bn(val))*fuseW[col] ->
//   atomicAdd facc[z*faccStride + global row].
__global__ __launch_bounds__(512) void gemm256(
    const bf16* __restrict__ A,
    const float* __restrict__ pairX, const float* __restrict__ pairY,
    const float* __restrict__ ps, const float* __restrict__ po,
    const bf16* __restrict__ BT,
    bf16* __restrict__ C,
    int K, int N, int rowOff,
    long long batchA, long long batchB, long long batchC,
    const float* __restrict__ scale, const float* __restrict__ offset,
    int lrelu,
    const float* __restrict__ fuseW, float* __restrict__ facc,
    long long faccStride)
{
    __shared__ bf16 As[256 * 64];   // 32 KiB
    __shared__ bf16 Bs[256 * 64];   // 32 KiB
    const int tid  = threadIdx.x;
    const int lane = tid & 63;
    const int wave = tid >> 6;
    const int wrow = wave >> 2, wcol = wave & 3;
    const int row0 = blockIdx.y * 256;
    const int col0 = blockIdx.x * 256;
    const int q = lane >> 4, l16 = lane & 15;
    const int z = blockIdx.z;

    const bf16* Ap = A + (size_t)z * (size_t)batchA;
    const bf16* Bp = BT + (size_t)z * (size_t)batchB;

    f32x4 acc[8][4];
#pragma unroll
    for (int mi = 0; mi < 8; ++mi)
#pragma unroll
        for (int ni = 0; ni < 4; ++ni)
#pragma unroll
            for (int e = 0; e < 4; ++e) acc[mi][ni][e] = 0.f;

    for (int kk = 0; kk < K; kk += 64) {
        if (pairX) {
#pragma unroll
            for (int t = 0; t < 4; ++t) {
                int c = tid + t * 512;      // 2048 tasks: r=c>>3, chunk=c&7
                int r = c >> 3, ch = c & 7;
                int gr = rowOff + row0 + r;
                const float* xp = pairX + (size_t)(gr >> 8) * K + kk + ch * 8;
                const float* yp = pairY + (size_t)(gr & 255) * K + kk + ch * 8;
                f32x4 x0 = *(const f32x4*)xp, x1 = *(const f32x4*)(xp + 4);
                f32x4 y0 = *(const f32x4*)yp, y1 = *(const f32x4*)(yp + 4);
                f32x4 sa = *(const f32x4*)(ps + kk + ch * 8);
                f32x4 sb = *(const f32x4*)(ps + kk + ch * 8 + 4);
                f32x4 oa = *(const f32x4*)(po + kk + ch * 8);
                f32x4 ob = *(const f32x4*)(po + kk + ch * 8 + 4);
                bf16x8 dv;
#pragma unroll
                for (int j = 0; j < 4; ++j) {
                    float d0 = x0[j] - y0[j];
                    float d1 = x1[j] - y1[j];
                    dv[j]     = (bf16)(d0 * d0 * sa[j] + oa[j]);
                    dv[j + 4] = (bf16)(d1 * d1 * sb[j] + ob[j]);
                }
                *(bf16x8*)&As[r * 64 + ((ch ^ (r & 7)) * 8)] = dv;
            }
        } else {
#pragma unroll
            for (int t = 0; t < 4; ++t) {
                int idx = t * 512 + tid;
                int r = idx >> 3, sch = idx & 7;
                int gch = sch ^ (r & 7);
                async_load16(Ap + (size_t)(row0 + r) * K + kk + gch * 8,
                             &As[idx * 8]);
            }
        }
#pragma unroll
        for (int t = 0; t < 4; ++t) {
            int idx = t * 512 + tid;
            int r = idx >> 3, sch = idx & 7;
            int gch = sch ^ (r & 7);
            async_load16(Bp + (size_t)(col0 + r) * K + kk + gch * 8,
                         &Bs[idx * 8]);
        }
        __syncthreads();

#pragma unroll
        for (int s = 0; s < 2; ++s) {
            bf16x8 af[8], bfr[4];
#pragma unroll
            for (int mi = 0; mi < 8; ++mi) {
                int r = wrow * 128 + mi * 16 + l16;
                af[mi] = *(const bf16x8*)&As[r * 64 + (((s * 4 + q) ^ (r & 7)) * 8)];
            }
#pragma unroll
            for (int ni = 0; ni < 4; ++ni) {
                int rc = wcol * 64 + ni * 16 + l16;
                bfr[ni] = *(const bf16x8*)&Bs[rc * 64 + (((s * 4 + q) ^ (rc & 7)) * 8)];
            }
#pragma unroll
            for (int mi = 0; mi < 8; ++mi)
#pragma unroll
                for (int ni = 0; ni < 4; ++ni)
                    acc[mi][ni] = __builtin_amdgcn_mfma_f32_16x16x32_bf16(
                        af[mi], bfr[ni], acc[mi][ni], 0, 0, 0);
        }
        __syncthreads();
    }

    // C/D layout (m89-verified): col = lane&15, row = (lane>>4)*4 + reg
    if (fuseW) {
#pragma unroll
        for (int mi = 0; mi < 8; ++mi)
#pragma unroll
            for (int i = 0; i < 4; ++i) {
                float rs = 0.f;
#pragma unroll
                for (int ni = 0; ni < 4; ++ni) {
                    int cc = col0 + wcol * 64 + ni * 16 + l16;
                    float val = acc[mi][ni][i] * scale[cc] + offset[cc];
                    val = val > 0.f ? val : 0.1f * val;
                    rs += val * fuseW[cc];
                }
                rs += __shfl_xor(rs, 1, 64);
                rs += __shfl_xor(rs, 2, 64);
                rs += __shfl_xor(rs, 4, 64);
                rs += __shfl_xor(rs, 8, 64);
                if (l16 == 0) {
                    int r = row0 + wrow * 128 + mi * 16 + q * 4 + i;
                    atomicAdd(facc + (size_t)z * faccStride + r, rs);
                }
            }
        return;
    }
    bf16* Cp = C + (size_t)z * (size_t)batchC;
#pragma unroll
    for (int mi = 0; mi < 8; ++mi)
#pragma unroll
        for (int ni = 0; ni < 4; ++ni)
#pragma unroll
            for (int i = 0; i < 4; ++i) {
                int r = row0 + wrow * 128 + mi * 16 + q * 4 + i;
                int cc = col0 + wcol * 64 + ni * 16 + l16;
                float val = acc[mi][ni][i];
                if (scale) val = val * scale[cc] + offset[cc];
                if (lrelu) val = val > 0.f ? val : 0.1f * val;
                Cp[(size_t)r * N + cc] = (bf16)val;
            }
}

// ---------- gemm_aff (R12-verified): symmetric affinity, 256x128, BK=64 ----
__global__ __launch_bounds__(512) void gemm_aff(
    const float* __restrict__ pairX,
    const float* __restrict__ ps, const float* __restrict__ po,
    const bf16* __restrict__ BT,
    int K,
    const float* __restrict__ scale, const float* __restrict__ offset,
    const float* __restrict__ sclW, float* __restrict__ w_acc)
{
    __shared__ bf16 As[256 * 64];   // 32 KiB
    __shared__ bf16 Bs[128 * 64];   // 16 KiB
    const int tid  = threadIdx.x;
    const int lane = tid & 63;
    const int wave = tid >> 6;
    const int wrow = wave >> 1, wcol = wave & 1;
    const int q = lane >> 4, l16 = lane & 15;
    const int col0 = blockIdx.x * 128;

    int ta = 0, rem = blockIdx.y;
    while (rem >= 16 - ta) { rem -= 16 - ta; ++ta; }
    const int tb = ta + rem;

    f32x4 acc[4][4];
#pragma unroll
    for (int mi = 0; mi < 4; ++mi)
#pragma unroll
        for (int ni = 0; ni < 4; ++ni)
#pragma unroll
            for (int e = 0; e < 4; ++e) acc[mi][ni][e] = 0.f;

    for (int kk = 0; kk < K; kk += 64) {
#pragma unroll
        for (int t = 0; t < 4; ++t) {
            int c = tid + t * 512;          // 2048 tasks: r=c>>3, ch=c&7
            int r = c >> 3, ch = c & 7;
            int g1 = ta * 16 + (r >> 4), g2 = tb * 16 + (r & 15);
            const float* xp = pairX + (size_t)g1 * K + kk + ch * 8;
            const float* yp = pairX + (size_t)g2 * K + kk + ch * 8;
            f32x4 x0 = *(const f32x4*)xp, x1 = *(const f32x4*)(xp + 4);
            f32x4 y0 = *(const f32x4*)yp, y1 = *(const f32x4*)(yp + 4);
            f32x4 sa = *(const f32x4*)(ps + kk + ch * 8);
            f32x4 sb = *(const f32x4*)(ps + kk + ch * 8 + 4);
            f32x4 oa = *(const f32x4*)(po + kk + ch * 8);
            f32x4 ob = *(const f32x4*)(po + kk + ch * 8 + 4);
            bf16x8 dv;
#pragma unroll
            for (int j = 0; j < 4; ++j) {
                float d0 = x0[j] - y0[j];
                float d1 = x1[j] - y1[j];
                dv[j]     = (bf16)(d0 * d0 * sa[j] + oa[j]);
                dv[j + 4] = (bf16)(d1 * d1 * sb[j] + ob[j]);
            }
            *(bf16x8*)&As[r * 64 + ((ch ^ (r & 7)) * 8)] = dv;
        }
#pragma unroll
        for (int t = 0; t < 2; ++t) {
            int idx = t * 512 + tid;        // 1024 chunks
            int r = idx >> 3, sch = idx & 7;
            int gch = sch ^ (r & 7);
            async_load16(BT + (size_t)(col0 + r) * K + kk + gch * 8,
                         &Bs[idx * 8]);
        }
        __syncthreads();

#pragma unroll
        for (int s = 0; s < 2; ++s) {
            bf16x8 af[4], bfr[4];
#pragma unroll
            for (int mi = 0; mi < 4; ++mi) {
                int r = wrow * 64 + mi * 16 + l16;
                af[mi] = *(const bf16x8*)&As[r * 64 + (((s * 4 + q) ^ (r & 7)) * 8)];
            }
#pragma unroll
            for (int ni = 0; ni < 4; ++ni) {
                int rc = wcol * 64 + ni * 16 + l16;
                bfr[ni] = *(const bf16x8*)&Bs[rc * 64 + (((s * 4 + q) ^ (rc & 7)) * 8)];
            }
#pragma unroll
            for (int mi = 0; mi < 4; ++mi)
#pragma unroll
                for (int ni = 0; ni < 4; ++ni)
                    acc[mi][ni] = __builtin_amdgcn_mfma_f32_16x16x32_bf16(
                        af[mi], bfr[ni], acc[mi][ni], 0, 0, 0);
        }
        __syncthreads();
    }

#pragma unroll
    for (int mi = 0; mi < 4; ++mi)
#pragma unroll
        for (int i = 0; i < 4; ++i) {
            float rs = 0.f;
#pragma unroll
            for (int ni = 0; ni < 4; ++ni) {
                int cc = col0 + wcol * 64 + ni * 16 + l16;
                float val = acc[mi][ni][i] * scale[cc] + offset[cc];
                val = val > 0.f ? val : 0.1f * val;
                rs += val * sclW[cc];
            }
            rs += __shfl_xor(rs, 1, 64);
            rs += __shfl_xor(rs, 2, 64);
            rs += __shfl_xor(rs, 4, 64);
            rs += __shfl_xor(rs, 8, 64);
            if (l16 == 0) {
                int r = wrow * 64 + mi * 16 + q * 4 + i;
                int g1 = ta * 16 + (r >> 4), g2 = tb * 16 + (r & 15);
                atomicAdd(w_acc + g1 * 256 + g2, rs);
            }
        }
}

extern "C" void kernel_launch(void* const* d_in, const int* in_sizes, int n_in,
                              void* d_out, int out_size, void* d_ws, size_t ws_size,
                              hipStream_t stream)
{
    const float* f_p   = (const float*)d_in[0];
    const float* f_g   = (const float*)d_in[1];
    const float* bn_g  = (const float*)d_in[2];
    const float* bn_b  = (const float*)d_in[3];
    const float* bn_m  = (const float*)d_in[4];
    const float* bn_v  = (const float*)d_in[5];
    const float* rf_W1 = (const float*)d_in[6];
    const float* rf_b1 = (const float*)d_in[7];
    const float* rf1_g = (const float*)d_in[8];
    const float* rf1_b = (const float*)d_in[9];
    const float* rf1_m = (const float*)d_in[10];
    const float* rf1_v = (const float*)d_in[11];
    const float* rf_W2 = (const float*)d_in[12];
    const float* rf_b2 = (const float*)d_in[13];
    const float* rf2_g = (const float*)d_in[14];
    const float* rf2_b = (const float*)d_in[15];
    const float* rf2_m = (const float*)d_in[16];
    const float* rf2_v = (const float*)d_in[17];
    const float* sfc_W = (const float*)d_in[18];
    const float* sfc_b = (const float*)d_in[19];
    const float* sbn_g = (const float*)d_in[20];
    const float* sbn_b = (const float*)d_in[21];
    const float* sbn_m = (const float*)d_in[22];
    const float* sbn_v = (const float*)d_in[23];
    const float* scl_W = (const float*)d_in[24];
    const float* scl_b = (const float*)d_in[25];
    const float* ffc_W = (const float*)d_in[26];
    const float* ffc_b = (const float*)d_in[27];
    const float* fbn_g = (const float*)d_in[28];
    const float* fbn_b = (const float*)d_in[29];
    const float* fbn_m = (const float*)d_in[30];
    const float* fbn_v = (const float*)d_in[31];
    const float* cls_W = (const float*)d_in[32];
    const float* cls_b = (const float*)d_in[33];

    const size_t MB = 1ull << 20;
    char* ws = (char*)d_ws;
    float* SC      = (float*)(ws);
    float *s0 = SC,        *o0 = SC + 1024;
    float *s1 = SC + 2048, *o1 = SC + 3072;
    float *s2 = SC + 4096, *o2 = SC + 5120;
    float *s3 = SC + 6144, *o3 = SC + 6656;
    float *s4 = SC + 7168, *o4 = SC + 7680;
    float* w_acc   = (float*)(ws + 65536);       // 256 KiB
    float* out_acc = (float*)(ws + 327680);      // 128 KiB
    bf16* wT       = (bf16*)(ws + 458752);       // 128 KiB
    bf16* W1T      = (bf16*)(ws + 1 * MB);
    bf16* W2T      = (bf16*)(ws + 3 * MB);
    bf16* sfcT     = (bf16*)(ws + 5 * MB);
    bf16* ffcT     = (bf16*)(ws + 6 * MB);

    int nc;
    if      (ws_size >= 170 * MB) nc = 1;        // confirmed since R3
    else if (ws_size >= 90 * MB)  nc = 2;
    else                          nc = 4;
    const int pc = 128 / nc;
    const int R  = pc * 256;
    const size_t hbytes = (size_t)R * 1024 * 2;
    bf16* bufA = (bf16*)(ws + 8 * MB);                    // h
    bf16* bufB = (bf16*)(ws + 8 * MB + hbytes);           // t
    bf16* bufC = (bf16*)(ws + 8 * MB + 2 * hbytes);       // uT [pc][512][256]

    // 1. BN folds
    prep_kernel<<<dim3(4), 256, 0, stream>>>(bn_g, bn_b, bn_m, bn_v, nullptr, s0, o0, 1024);
    prep_kernel<<<dim3(4), 256, 0, stream>>>(rf1_g, rf1_b, rf1_m, rf1_v, rf_b1, s1, o1, 1024);
    prep_kernel<<<dim3(4), 256, 0, stream>>>(rf2_g, rf2_b, rf2_m, rf2_v, rf_b2, s2, o2, 1024);
    prep_kernel<<<dim3(2), 256, 0, stream>>>(sbn_g, sbn_b, sbn_m, sbn_v, sfc_b, s3, o3, 512);
    prep_kernel<<<dim3(2), 256, 0, stream>>>(fbn_g, fbn_b, fbn_m, fbn_v, ffc_b, s4, o4, 512);

    // 2. weight transposes (f32 -> bf16)
    wtrans_kernel<<<dim3(4, 1024), 256, 0, stream>>>(rf_W1, W1T, 1024, 1024);
    wtrans_kernel<<<dim3(4, 1024), 256, 0, stream>>>(rf_W2, W2T, 1024, 1024);
    wtrans_kernel<<<dim3(4, 512), 256, 0, stream>>>(sfc_W, sfcT, 1024, 512);
    wtrans_kernel<<<dim3(4, 512), 256, 0, stream>>>(ffc_W, ffcT, 1024, 512);

    // 3. zero accumulators (w_acc + out_acc contiguous)
    hipMemsetAsync(ws + 65536, 0, 393216, stream);

    // 4. symmetric affinity (R12-verified): grid (4,136)
    gemm_aff<<<dim3(4, 136), 512, 0, stream>>>(
        f_g, s0, o0, sfcT, 1024, s3, o3, scl_W, w_acc);
    // 5. wT[g2][g1] = bf16(w[canon] + scl_b)
    wconv_kernel<<<dim3(256), 256, 0, stream>>>(w_acc, scl_b, wT);

    // 6. probe chunks
    for (int ci = 0; ci < nc; ++ci) {
        // h = lrelu(rf1(d @ W1 + b1))   [R,1024] (pair-fused)
        gemm256<<<dim3(4, R / 256), 512, 0, stream>>>(
            nullptr, f_p, f_g, s0, o0, W1T, bufA, 1024, 1024, ci * R,
            0, 0, 0, s1, o1, 1, nullptr, nullptr, 0);
        // t = lrelu(rf2(h @ W2 + b2))   [R,1024]
        gemm256<<<dim3(4, R / 256), 512, 0, stream>>>(
            bufA, nullptr, nullptr, nullptr, nullptr, W2T, bufB, 1024, 1024, 0,
            0, 0, 0, s2, o2, 1, nullptr, nullptr, 0);
        // uT_p = ffcT @ t_p^T           [pc][512][256]  (batched; no utrans)
        gemm256<<<dim3(1, 2, pc), 512, 0, stream>>>(
            ffcT, nullptr, nullptr, nullptr, nullptr, bufB, bufC, 1024, 256, 0,
            0, (long long)256 * 1024, (long long)512 * 256,
            nullptr, nullptr, 0, nullptr, nullptr, 0);
        // feat_p = lrelu(fbn(wT @ uT_p^T + b)) . cls_W -> out_acc  (batched)
        gemm256<<<dim3(2, 1, pc), 512, 0, stream>>>(
            wT, nullptr, nullptr, nullptr, nullptr, bufC, nullptr, 256, 512, 0,
            0, (long long)512 * 256, 0,
            s4, o4, 1, cls_W, out_acc + (size_t)ci * pc * 256, 256);
    }
    // 7. d_out = out_acc + cls_b
    finout_kernel<<<dim3(128), 256, 0, stream>>>(out_acc, cls_b, (float*)d_out);
}